// Round 2
// baseline (1021.506 us; speedup 1.0000x reference)
//
#include <hip/hip_runtime.h>
#include <hip/hip_cooperative_groups.h>

namespace cg = cooperative_groups;

// ---------------------------------------------------------------------------
// DynamicHippocampus, single cooperative kernel.
// EC --PP--> DG --MF--> CA3 (--RC--> CA3) --SC--> CA1, T=4 steps.
// All neuron state lives in registers (fixed thread->neuron mapping).
// Spike flags published at grid.sync points; transmit + its trailing sync
// only execute when the source population actually spiked (data-dependent,
// fully general), so the silent path costs 13 grid syncs total.
// ---------------------------------------------------------------------------

#define N_EC  100000
#define N_DG  400000
#define N_CA3 120000
#define N_CA1 100000

constexpr int PP_NNZ = 10000000, MF_NNZ = 8000000, RC_NNZ = 6000000, SC_NNZ = 6000000;
constexpr int T_STEPS = 4;
constexpr int NBLK = 512, TPB = 256;
constexpr int NTH  = NBLK * TPB;                 // 131072 threads
constexpr int DGS  = (N_DG + NTH - 1) / NTH;    // 4 DG slots per thread

// workspace layout (float offsets)
constexpr size_t OFF_DG_I = 0;
constexpr size_t OFF_C3_I = OFF_DG_I + N_DG;
constexpr size_t OFF_C1_I = OFF_C3_I + N_CA3;
constexpr size_t OFF_SUMS = OFF_C1_I + N_CA1;   // 16 floats (12 used: [t*3+pop])
constexpr size_t OFF_FLAG = OFF_SUMS + 16;      // 16 ints
constexpr size_t OFF_MASK = OFF_FLAG + 16;      // even -> 8B aligned u64 region
constexpr size_t MW_EC = 0,    MW_EC_N = 1564;  // ceil(100000/64)=1563
constexpr size_t MW_DG = 1564, MW_DG_N = 6250;
constexpr size_t MW_C3 = 7814, MW_C3_N = 1876;  // ceil(120000/64)=1875

struct SimParams {
  const float* drive;
  const int *pp_src, *pp_tgt; const float* pp_val;
  const int *mf_src, *mf_tgt; const float* mf_val;
  const int *rc_src, *rc_tgt; const float* rc_val;
  const int *sc_src, *sc_tgt; const float* sc_val;
  const float *ec_c, *ec_d, *dg_c, *dg_d, *c3_c, *c3_d, *c1_c, *c1_d;
  float* out; float* ws;
};

__device__ __forceinline__ void izh_step(float& vv, float& uu, float I,
                                         float c, float d, bool& s) {
  vv = vv + (0.04f * vv * vv + 5.0f * vv + 140.0f - uu + I) * 0.5f;   // DT=0.5
  vv = fminf(fmaxf(vv, -90.0f), 40.0f);
  uu = uu + 0.02f * (0.2f * vv - uu) * 0.5f;    // A=0.02, B=0.2, post-clamp v
  s = (vv >= 30.0f);
  if (s) { vv = c; uu = uu + d; }
}

__device__ __forceinline__ float wave_sum(float x) {
  for (int o = 32; o > 0; o >>= 1) x += __shfl_down(x, o);
  return x;
}

// sparse COO scatter: I[tgt] += val where src spiked; accumulate total for mean
__device__ void transmit(const int* __restrict__ src, const int* __restrict__ tgt,
                         const float* __restrict__ val, int nnz4,
                         const unsigned long long* __restrict__ mask,
                         float* __restrict__ I, float* __restrict__ sum_slot,
                         int tid) {
  float local = 0.0f;
  for (int i = tid; i < nnz4; i += NTH) {
    const int4   s4 = reinterpret_cast<const int4*>(src)[i];
    const int4   t4 = reinterpret_cast<const int4*>(tgt)[i];
    const float4 v4 = reinterpret_cast<const float4*>(val)[i];
    const int   ss[4] = {s4.x, s4.y, s4.z, s4.w};
    const int   tt[4] = {t4.x, t4.y, t4.z, t4.w};
    const float vv[4] = {v4.x, v4.y, v4.z, v4.w};
#pragma unroll
    for (int k = 0; k < 4; ++k) {
      if ((mask[ss[k] >> 6] >> (ss[k] & 63)) & 1ull) {
        atomicAdd(&I[tt[k]], vv[k]);
        local += vv[k];
      }
    }
  }
  local = wave_sum(local);
  if ((threadIdx.x & 63) == 0 && local != 0.0f) atomicAdd(sum_slot, local);
}

__global__ __launch_bounds__(TPB, 2)
void sim_kernel(SimParams p) {
  cg::grid_group grid = cg::this_grid();
  const int tid  = blockIdx.x * blockDim.x + threadIdx.x;
  const int lane = threadIdx.x & 63;

  float* ws   = p.ws;
  float* dg_I = ws + OFF_DG_I;
  float* c3_I = ws + OFF_C3_I;
  float* c1_I = ws + OFF_C1_I;
  float* sums = ws + OFF_SUMS;
  int*   flags = (int*)(ws + OFF_FLAG);
  unsigned long long* mbase = (unsigned long long*)(ws + OFF_MASK);
  unsigned long long* ec_m = mbase + MW_EC;
  unsigned long long* dg_m = mbase + MW_DG;
  unsigned long long* c3_m = mbase + MW_C3;

  // ---- init: zero I buffers, sums, flags ----
  for (int i = tid; i < N_DG;  i += NTH) dg_I[i] = 0.0f;
  for (int i = tid; i < N_CA3; i += NTH) c3_I[i] = 0.0f;
  for (int i = tid; i < N_CA1; i += NTH) c1_I[i] = 0.0f;
  if (tid < 16) { sums[tid] = 0.0f; flags[tid] = 0; }

  // ---- register-resident neuron state ----
  const bool ec_ok = tid < N_EC;
  float ecv = -65.0f, ecu = -13.0f, ecc = 0.0f, ecd = 0.0f;
  if (ec_ok) { ecc = p.ec_c[tid]; ecd = p.ec_d[tid]; }

  float dgv[DGS], dgu[DGS], dgc[DGS], dgd[DGS];
#pragma unroll
  for (int k = 0; k < DGS; ++k) {
    int idx = tid + k * NTH;
    dgv[k] = -65.0f; dgu[k] = -13.0f; dgc[k] = 0.0f; dgd[k] = 0.0f;
    if (idx < N_DG) { dgc[k] = p.dg_c[idx]; dgd[k] = p.dg_d[idx]; }
  }
  const bool c3_ok = tid < N_CA3;
  float c3v = -65.0f, c3u = -13.0f, c3c = 0.0f, c3dd = 0.0f;
  if (c3_ok) { c3c = p.c3_c[tid]; c3dd = p.c3_d[tid]; }
  const bool c1_ok = tid < N_CA1;
  float c1v = -65.0f, c1u = -13.0f, c1c = 0.0f, c1dd = 0.0f;
  if (c1_ok) { c1c = p.c1_c[tid]; c1dd = p.c1_d[tid]; }

  // replicated scalar LIF populations (uniform input -> scalar state)
  float iv_dg = 0.0f, iv_c3 = 0.0f, iv_c1 = 0.0f;

  grid.sync();   // init visible before any flag/atomics use

  for (int t = 0; t < T_STEPS; ++t) {
    // ---------------- EC (external drive) ----------------
    {
      bool s = false;
      if (ec_ok) izh_step(ecv, ecu, p.drive[(size_t)t * N_EC + tid], ecc, ecd, s);
      unsigned long long m = __ballot(s);
      if (lane == 0 && ec_ok) {
        ec_m[tid >> 6] = m;
        if (m) atomicOr(&flags[t * 3 + 0], 1);
      }
    }
    grid.sync();                                   // publish f_ec
    const int fe = flags[t * 3 + 0];
    if (fe) {
      transmit(p.pp_src, p.pp_tgt, p.pp_val, PP_NNZ / 4, ec_m, dg_I, &sums[t * 3 + 0], tid);
      grid.sync();                                 // dg_I + sum final
    }
    // ---------------- DG (+ scalar LIF inhibition) ----------------
    {
      float mean = sums[t * 3 + 0] * (1.0f / (float)N_DG);
      iv_dg = 0.9f * iv_dg + 0.1f * mean;
      bool ls = (iv_dg >= 1.0f);
      float inh = ls ? 2.0f : 0.0f;
      if (ls) iv_dg = 0.0f;
#pragma unroll
      for (int k = 0; k < DGS; ++k) {
        int idx = tid + k * NTH;
        bool s = false;
        if (idx < N_DG) {
          float I = (fe ? dg_I[idx] : 0.0f) - inh;
          if (fe) dg_I[idx] = 0.0f;                // ready for next step
          izh_step(dgv[k], dgu[k], I, dgc[k], dgd[k], s);
        }
        unsigned long long m = __ballot(s);
        if (lane == 0 && idx < N_DG) {
          dg_m[idx >> 6] = m;
          if (m) atomicOr(&flags[t * 3 + 1], 1);
        }
      }
    }
    grid.sync();                                   // publish f_dg
    const int fd  = flags[t * 3 + 1];
    const int fcp = (t > 0) ? flags[(t - 1) * 3 + 2] : 0;   // CA3 spikes from t-1
    if (fd)  transmit(p.mf_src, p.mf_tgt, p.mf_val, MF_NNZ / 4, dg_m, c3_I, &sums[t * 3 + 1], tid);
    if (fcp) transmit(p.rc_src, p.rc_tgt, p.rc_val, RC_NNZ / 4, c3_m, c3_I, &sums[t * 3 + 1], tid);
    if (fd | fcp) grid.sync();                     // c3_I + sum final
    // ---------------- CA3 ----------------
    {
      float mean = sums[t * 3 + 1] * (1.0f / (float)N_CA3);
      iv_c3 = 0.9f * iv_c3 + 0.1f * mean;
      bool ls = (iv_c3 >= 1.0f);
      float inh = ls ? 2.0f : 0.0f;
      if (ls) iv_c3 = 0.0f;
      bool s = false;
      if (c3_ok) {
        float I = ((fd | fcp) ? c3_I[tid] : 0.0f) - inh;
        if (fd | fcp) c3_I[tid] = 0.0f;
        izh_step(c3v, c3u, I, c3c, c3dd, s);
      }
      unsigned long long m = __ballot(s);
      if (lane == 0 && c3_ok) {                    // overwrites AFTER rc consumed it
        c3_m[tid >> 6] = m;
        if (m) atomicOr(&flags[t * 3 + 2], 1);
      }
    }
    grid.sync();                                   // publish f_c3
    const int fc = flags[t * 3 + 2];
    if (fc) {
      transmit(p.sc_src, p.sc_tgt, p.sc_val, SC_NNZ / 4, c3_m, c1_I, &sums[t * 3 + 2], tid);
      grid.sync();                                 // c1_I + sum final
    }
    // ---------------- CA1 ----------------
    {
      float mean = sums[t * 3 + 2] * (1.0f / (float)N_CA1);
      iv_c1 = 0.9f * iv_c1 + 0.1f * mean;
      bool ls = (iv_c1 >= 1.0f);
      float inh = ls ? 2.0f : 0.0f;
      if (ls) iv_c1 = 0.0f;
      if (c1_ok) {
        float I = (fc ? c1_I[tid] : 0.0f) - inh;
        if (fc) c1_I[tid] = 0.0f;
        bool s = false;
        izh_step(c1v, c1u, I, c1c, c1dd, s);
        if (t == T_STEPS - 1) p.out[tid] = c1v;    // final CA1 membrane potential
      }
    }
    // no sync needed: next-step EC touches only its own registers + drive
  }
}

// ---------------------------------------------------------------------------
extern "C" void kernel_launch(void* const* d_in, const int* in_sizes, int n_in,
                              void* d_out, int out_size, void* d_ws, size_t ws_size,
                              hipStream_t stream) {
  SimParams prm;
  prm.drive  = (const float*)d_in[0];
  prm.pp_src = (const int*)d_in[1];  prm.pp_tgt = (const int*)d_in[2];  prm.pp_val = (const float*)d_in[3];
  prm.mf_src = (const int*)d_in[4];  prm.mf_tgt = (const int*)d_in[5];  prm.mf_val = (const float*)d_in[6];
  prm.rc_src = (const int*)d_in[7];  prm.rc_tgt = (const int*)d_in[8];  prm.rc_val = (const float*)d_in[9];
  prm.sc_src = (const int*)d_in[10]; prm.sc_tgt = (const int*)d_in[11]; prm.sc_val = (const float*)d_in[12];
  prm.ec_c = (const float*)d_in[13]; prm.ec_d = (const float*)d_in[14];
  prm.dg_c = (const float*)d_in[15]; prm.dg_d = (const float*)d_in[16];
  prm.c3_c = (const float*)d_in[17]; prm.c3_d = (const float*)d_in[18];
  prm.c1_c = (const float*)d_in[19]; prm.c1_d = (const float*)d_in[20];
  prm.out = (float*)d_out;
  prm.ws  = (float*)d_ws;

  void* args[] = { &prm };
  hipLaunchCooperativeKernel((void*)sim_kernel, dim3(NBLK), dim3(TPB), args, 0, stream);
}

// Round 3
// 263.757 us; speedup vs baseline: 3.8729x; 3.8729x over previous
//
#include <hip/hip_runtime.h>

// ---------------------------------------------------------------------------
// DynamicHippocampus: EC --PP--> DG --MF--> CA3 (--RC--> CA3) --SC--> CA1.
// T=4 Izhikevich steps, scalar-collapsed LIF inhibition.
//
// Structure (3 dispatches, fully general):
//  K0  init: zero flags/sums/barrier words.
//  K1  speculative: per-neuron EC trajectory (drive only; c/d untouched
//      pre-spike) + one scalar silent-trajectory check covering DG/CA3/CA1
//      (identical init, zero input => identical pre-spike dynamics).
//      Any spike anywhere -> deviation flag. Speculatively writes out[] =
//      silent CA1 final v.
//  K2  fallback: persistent general simulator, gated on deviation (returns
//      immediately when silent). Custom sense-reversing device-scope barrier;
//      512 blocks x 256 thr @ __launch_bounds__(256,2) = exactly 2 blocks/CU
//      on 256 CUs => co-residency guaranteed by resource arithmetic.
//
// Completeness of the deviation test: the first spike in the true dynamics
// happens while all transmit inputs are still zero (spikes are the only
// cross-population coupling; LIF iv stays 0 without input), so K1's
// zero-input simulation observes it.
// ---------------------------------------------------------------------------

#define N_EC  100000
#define N_DG  400000
#define N_CA3 120000
#define N_CA1 100000

constexpr int PP_NNZ = 10000000, MF_NNZ = 8000000, RC_NNZ = 6000000, SC_NNZ = 6000000;
constexpr int T_STEPS = 4;
constexpr int NBLK = 512, TPB = 256;           // K2 persistent grid
constexpr int NTH  = NBLK * TPB;               // 131072 threads
constexpr int DGS  = (N_DG + NTH - 1) / NTH;   // 4 DG slots/thread in K2

// ---- workspace layout (float offsets) ----
constexpr size_t OFF_DG_I = 0;
constexpr size_t OFF_C3_I = OFF_DG_I + N_DG;
constexpr size_t OFF_C1_I = OFF_C3_I + N_CA3;
constexpr size_t OFF_SUMS = OFF_C1_I + N_CA1;   // 16 floats: sums[t*3+pop]
constexpr size_t OFF_FLAG = OFF_SUMS + 16;      // 16 ints: [t*3+pop], [12]=deviation
constexpr size_t OFF_BAR  = OFF_FLAG + 16;      // 16 ints: [0]=count, [1]=sense
constexpr size_t OFF_MASK = OFF_BAR + 16;       // even -> 8B-aligned u64 region
constexpr size_t MW_EC = 0,    MW_EC_N = 1564;
constexpr size_t MW_DG = 1564, MW_DG_N = 6250;
constexpr size_t MW_C3 = 7814, MW_C3_N = 1876;

struct SimParams {
  const float* drive;
  const int *pp_src, *pp_tgt; const float* pp_val;
  const int *mf_src, *mf_tgt; const float* mf_val;
  const int *rc_src, *rc_tgt; const float* rc_val;
  const int *sc_src, *sc_tgt; const float* sc_val;
  const float *ec_c, *ec_d, *dg_c, *dg_d, *c3_c, *c3_d, *c1_c, *c1_d;
  float* out; float* ws;
};

__device__ __forceinline__ void izh_step(float& vv, float& uu, float I,
                                         float c, float d, bool& s) {
  vv = vv + (0.04f * vv * vv + 5.0f * vv + 140.0f - uu + I) * 0.5f;   // DT=0.5
  vv = fminf(fmaxf(vv, -90.0f), 40.0f);
  uu = uu + 0.02f * (0.2f * vv - uu) * 0.5f;    // A=0.02, B=0.2, post-clamp v
  s = (vv >= 30.0f);
  if (s) { vv = c; uu = uu + d; }
}

// ---------------------------------------------------------------------------
__global__ __launch_bounds__(64)
void init_kernel(float* __restrict__ ws) {
  int i = threadIdx.x;
  if (i < 16) {
    ((float*)(ws + OFF_SUMS))[i] = 0.0f;
    ((int*)(ws + OFF_FLAG))[i] = 0;
    ((int*)(ws + OFF_BAR))[i] = 0;
  }
}

// ---------------------------------------------------------------------------
// K1: speculative silent-path simulation + deviation detection.
__global__ __launch_bounds__(256)
void spec_kernel(const float* __restrict__ drive, float* __restrict__ out,
                 float* __restrict__ ws) {
  int i = blockIdx.x * blockDim.x + threadIdx.x;
  bool dev = false;

  // EC neuron i: 4 steps with external drive; c/d unused pre-spike.
  if (i < N_EC) {
    float v = -65.0f, u = -13.0f;
#pragma unroll
    for (int t = 0; t < T_STEPS; ++t) {
      bool s;
      izh_step(v, u, drive[(size_t)t * N_EC + i], 0.0f, 0.0f, s);
      if (s) { dev = true; break; }     // trajectory beyond first spike is K2's job
    }
  }

  // Common silent trajectory for DG/CA3/CA1 (identical init, I=0, same a,b;
  // c/d only matter post-spike). Register-only; redundant across threads.
  float sv = -65.0f, su = -13.0f;
#pragma unroll
  for (int t = 0; t < T_STEPS; ++t) {
    bool s;
    izh_step(sv, su, 0.0f, 0.0f, 0.0f, s);
    if (s) dev = true;
  }

  unsigned long long m = __ballot(dev);
  if ((threadIdx.x & 63) == 0 && m)
    atomicOr((int*)(ws + OFF_FLAG) + 12, 1);

  // Speculative output: silent CA1 final membrane potential (uniform).
  if (i < N_CA1) out[i] = sv;
}

// ---------------------------------------------------------------------------
// Custom device-scope grid barrier (sense-reversing, centralized).
__device__ __forceinline__ void gbar(int* cnt, int* sense, int* lsense_sh) {
  __syncthreads();
  __threadfence();                               // publish my block's writes
  if (threadIdx.x == 0) {
    int ls = *lsense_sh ^ 1;
    *lsense_sh = ls;
    if (atomicAdd(cnt, 1) == NBLK - 1) {
      atomicExch(cnt, 0);                        // all arrived; reset for reuse
      __threadfence();
      atomicExch(sense, ls);                     // release waiters
    } else {
      while (atomicAdd(sense, 0) != ls) __builtin_amdgcn_s_sleep(8);
    }
  }
  __syncthreads();
  __threadfence();                               // acquire others' writes
}

__device__ __forceinline__ float wave_sum(float x) {
  for (int o = 32; o > 0; o >>= 1) x += __shfl_down(x, o);
  return x;
}

__device__ void transmit(const int* __restrict__ src, const int* __restrict__ tgt,
                         const float* __restrict__ val, int nnz4,
                         const unsigned long long* __restrict__ mask,
                         float* __restrict__ I, float* __restrict__ sum_slot,
                         int tid) {
  float local = 0.0f;
  for (int i = tid; i < nnz4; i += NTH) {
    const int4   s4 = reinterpret_cast<const int4*>(src)[i];
    const int4   t4 = reinterpret_cast<const int4*>(tgt)[i];
    const float4 v4 = reinterpret_cast<const float4*>(val)[i];
    const int   ss[4] = {s4.x, s4.y, s4.z, s4.w};
    const int   tt[4] = {t4.x, t4.y, t4.z, t4.w};
    const float vv[4] = {v4.x, v4.y, v4.z, v4.w};
#pragma unroll
    for (int k = 0; k < 4; ++k) {
      if ((mask[ss[k] >> 6] >> (ss[k] & 63)) & 1ull) {
        atomicAdd(&I[tt[k]], vv[k]);
        local += vv[k];
      }
    }
  }
  local = wave_sum(local);
  if ((threadIdx.x & 63) == 0 && local != 0.0f) atomicAdd(sum_slot, local);
}

// ---------------------------------------------------------------------------
// K2: general fallback, gated on the deviation flag (never runs when silent).
__global__ __launch_bounds__(TPB, 2)
void fallback_kernel(SimParams p) {
  float* ws = p.ws;
  int* flags = (int*)(ws + OFF_FLAG);
  if (flags[12] == 0) return;                    // silent: K1's output stands

  __shared__ int lsense;
  if (threadIdx.x == 0) lsense = 0;
  int* bcnt   = (int*)(ws + OFF_BAR) + 0;
  int* bsense = (int*)(ws + OFF_BAR) + 1;

  const int tid  = blockIdx.x * blockDim.x + threadIdx.x;
  const int lane = threadIdx.x & 63;

  float* dg_I = ws + OFF_DG_I;
  float* c3_I = ws + OFF_C3_I;
  float* c1_I = ws + OFF_C1_I;
  float* sums = ws + OFF_SUMS;
  unsigned long long* mbase = (unsigned long long*)(ws + OFF_MASK);
  unsigned long long* ec_m = mbase + MW_EC;
  unsigned long long* dg_m = mbase + MW_DG;
  unsigned long long* c3_m = mbase + MW_C3;

  // zero scatter buffers
  for (int i = tid; i < N_DG;  i += NTH) dg_I[i] = 0.0f;
  for (int i = tid; i < N_CA3; i += NTH) c3_I[i] = 0.0f;
  for (int i = tid; i < N_CA1; i += NTH) c1_I[i] = 0.0f;

  // register-resident neuron state
  const bool ec_ok = tid < N_EC;
  float ecv = -65.0f, ecu = -13.0f, ecc = 0.0f, ecd = 0.0f;
  if (ec_ok) { ecc = p.ec_c[tid]; ecd = p.ec_d[tid]; }
  float dgv[DGS], dgu[DGS], dgc[DGS], dgd[DGS];
#pragma unroll
  for (int k = 0; k < DGS; ++k) {
    int idx = tid + k * NTH;
    dgv[k] = -65.0f; dgu[k] = -13.0f; dgc[k] = 0.0f; dgd[k] = 0.0f;
    if (idx < N_DG) { dgc[k] = p.dg_c[idx]; dgd[k] = p.dg_d[idx]; }
  }
  const bool c3_ok = tid < N_CA3;
  float c3v = -65.0f, c3u = -13.0f, c3c = 0.0f, c3dd = 0.0f;
  if (c3_ok) { c3c = p.c3_c[tid]; c3dd = p.c3_d[tid]; }
  const bool c1_ok = tid < N_CA1;
  float c1v = -65.0f, c1u = -13.0f, c1c = 0.0f, c1dd = 0.0f;
  if (c1_ok) { c1c = p.c1_c[tid]; c1dd = p.c1_d[tid]; }

  float iv_dg = 0.0f, iv_c3 = 0.0f, iv_c1 = 0.0f;   // scalar LIF (replicated)

  gbar(bcnt, bsense, &lsense);   // init visible

  for (int t = 0; t < T_STEPS; ++t) {
    // ---------------- EC ----------------
    {
      bool s = false;
      if (ec_ok) izh_step(ecv, ecu, p.drive[(size_t)t * N_EC + tid], ecc, ecd, s);
      unsigned long long m = __ballot(s);
      if (lane == 0 && ec_ok) {
        ec_m[tid >> 6] = m;
        if (m) atomicOr(&flags[t * 3 + 0], 1);
      }
    }
    gbar(bcnt, bsense, &lsense);
    const int fe = flags[t * 3 + 0];
    if (fe) {
      transmit(p.pp_src, p.pp_tgt, p.pp_val, PP_NNZ / 4, ec_m, dg_I, &sums[t * 3 + 0], tid);
      gbar(bcnt, bsense, &lsense);
    }
    // ---------------- DG ----------------
    {
      float mean = sums[t * 3 + 0] * (1.0f / (float)N_DG);
      iv_dg = 0.9f * iv_dg + 0.1f * mean;
      bool ls = (iv_dg >= 1.0f);
      float inh = ls ? 2.0f : 0.0f;
      if (ls) iv_dg = 0.0f;
#pragma unroll
      for (int k = 0; k < DGS; ++k) {
        int idx = tid + k * NTH;
        bool s = false;
        if (idx < N_DG) {
          float I = (fe ? dg_I[idx] : 0.0f) - inh;
          if (fe) dg_I[idx] = 0.0f;
          izh_step(dgv[k], dgu[k], I, dgc[k], dgd[k], s);
        }
        unsigned long long m = __ballot(s);
        if (lane == 0 && idx < N_DG) {
          dg_m[idx >> 6] = m;
          if (m) atomicOr(&flags[t * 3 + 1], 1);
        }
      }
    }
    gbar(bcnt, bsense, &lsense);
    const int fd  = flags[t * 3 + 1];
    const int fcp = (t > 0) ? flags[(t - 1) * 3 + 2] : 0;
    if (fd)  transmit(p.mf_src, p.mf_tgt, p.mf_val, MF_NNZ / 4, dg_m, c3_I, &sums[t * 3 + 1], tid);
    if (fcp) transmit(p.rc_src, p.rc_tgt, p.rc_val, RC_NNZ / 4, c3_m, c3_I, &sums[t * 3 + 1], tid);
    if (fd | fcp) gbar(bcnt, bsense, &lsense);
    // ---------------- CA3 ----------------
    {
      float mean = sums[t * 3 + 1] * (1.0f / (float)N_CA3);
      iv_c3 = 0.9f * iv_c3 + 0.1f * mean;
      bool ls = (iv_c3 >= 1.0f);
      float inh = ls ? 2.0f : 0.0f;
      if (ls) iv_c3 = 0.0f;
      bool s = false;
      if (c3_ok) {
        float I = ((fd | fcp) ? c3_I[tid] : 0.0f) - inh;
        if (fd | fcp) c3_I[tid] = 0.0f;
        izh_step(c3v, c3u, I, c3c, c3dd, s);
      }
      unsigned long long m = __ballot(s);
      if (lane == 0 && c3_ok) {                  // written AFTER rc consumed t-1 mask
        c3_m[tid >> 6] = m;
        if (m) atomicOr(&flags[t * 3 + 2], 1);
      }
    }
    gbar(bcnt, bsense, &lsense);
    const int fc = flags[t * 3 + 2];
    if (fc) {
      transmit(p.sc_src, p.sc_tgt, p.sc_val, SC_NNZ / 4, c3_m, c1_I, &sums[t * 3 + 2], tid);
      gbar(bcnt, bsense, &lsense);
    }
    // ---------------- CA1 ----------------
    {
      float mean = sums[t * 3 + 2] * (1.0f / (float)N_CA1);
      iv_c1 = 0.9f * iv_c1 + 0.1f * mean;
      bool ls = (iv_c1 >= 1.0f);
      float inh = ls ? 2.0f : 0.0f;
      if (ls) iv_c1 = 0.0f;
      if (c1_ok) {
        float I = (fc ? c1_I[tid] : 0.0f) - inh;
        if (fc) c1_I[tid] = 0.0f;
        bool s = false;
        izh_step(c1v, c1u, I, c1c, c1dd, s);
        if (t == T_STEPS - 1) p.out[tid] = c1v;  // overwrite K1's speculative out
      }
    }
  }
}

// ---------------------------------------------------------------------------
extern "C" void kernel_launch(void* const* d_in, const int* in_sizes, int n_in,
                              void* d_out, int out_size, void* d_ws, size_t ws_size,
                              hipStream_t stream) {
  SimParams prm;
  prm.drive  = (const float*)d_in[0];
  prm.pp_src = (const int*)d_in[1];  prm.pp_tgt = (const int*)d_in[2];  prm.pp_val = (const float*)d_in[3];
  prm.mf_src = (const int*)d_in[4];  prm.mf_tgt = (const int*)d_in[5];  prm.mf_val = (const float*)d_in[6];
  prm.rc_src = (const int*)d_in[7];  prm.rc_tgt = (const int*)d_in[8];  prm.rc_val = (const float*)d_in[9];
  prm.sc_src = (const int*)d_in[10]; prm.sc_tgt = (const int*)d_in[11]; prm.sc_val = (const float*)d_in[12];
  prm.ec_c = (const float*)d_in[13]; prm.ec_d = (const float*)d_in[14];
  prm.dg_c = (const float*)d_in[15]; prm.dg_d = (const float*)d_in[16];
  prm.c3_c = (const float*)d_in[17]; prm.c3_d = (const float*)d_in[18];
  prm.c1_c = (const float*)d_in[19]; prm.c1_d = (const float*)d_in[20];
  prm.out = (float*)d_out;
  prm.ws  = (float*)d_ws;

  float* ws = (float*)d_ws;
  init_kernel<<<1, 64, 0, stream>>>(ws);
  spec_kernel<<<(N_EC + 255) / 256, 256, 0, stream>>>(prm.drive, prm.out, ws);
  fallback_kernel<<<NBLK, TPB, 0, stream>>>(prm);
}